// Round 5
// baseline (22780.437 us; speedup 1.0000x reference)
//
#include <hip/hip_runtime.h>
#include <hip/hip_bf16.h>

// Problem constants (match reference)
constexpr int Bsz = 32;
constexpr int T   = 4096;
constexpr int P   = 64;
constexpr int IN  = 128;
constexpr int H   = 256;
constexpr long M  = (long)Bsz * T;   // 131072 rows

// ---------------------------------------------------------------------------
// K1/K3: out[m][j] = sum_c X[m][c] * W[j][c] + b1[j] + b2[j]
// ---------------------------------------------------------------------------
template <int K>
__global__ __launch_bounds__(256) void gemm_pre(
    const float* __restrict__ X, const float* __restrict__ W,
    const float* __restrict__ b1, const float* __restrict__ b2,
    float* __restrict__ out) {
  constexpr int K4 = K / 4;
  __shared__ float4 a4[16][K4];
  __shared__ float  wch[256][33];
  const int tid = threadIdx.x;
  const long m0 = (long)blockIdx.x * 16;

  const float4* X4 = (const float4*)X;
#pragma unroll
  for (int i = 0; i < (16 * K4) / 256; ++i) {
    int idx = tid + 256 * i;
    int r = idx / K4, c = idx % K4;
    a4[r][c] = X4[(m0 + r) * K4 + c];
  }

  const int j = tid;
  const float bsum = b1[j] + b2[j];
  float acc[16];
#pragma unroll
  for (int r = 0; r < 16; ++r) acc[r] = 0.f;

  const float4* W4v = (const float4*)W;
  for (int kc = 0; kc < K4; kc += 8) {
    __syncthreads();
#pragma unroll
    for (int i = 0; i < 8; ++i) {
      int idx = tid + 256 * i;
      int jr = idx >> 3, c = idx & 7;
      float4 t4 = W4v[(long)jr * K4 + kc + c];
      wch[jr][4 * c + 0] = t4.x; wch[jr][4 * c + 1] = t4.y;
      wch[jr][4 * c + 2] = t4.z; wch[jr][4 * c + 3] = t4.w;
    }
    __syncthreads();
#pragma unroll
    for (int i4 = 0; i4 < 8; ++i4) {
      float wx = wch[j][4 * i4 + 0], wy = wch[j][4 * i4 + 1];
      float wz = wch[j][4 * i4 + 2], ww = wch[j][4 * i4 + 3];
#pragma unroll
      for (int r = 0; r < 16; ++r) {
        float4 av = a4[r][kc + i4];
        acc[r] += wx * av.x + wy * av.y + wz * av.z + ww * av.w;
      }
    }
  }
#pragma unroll
  for (int r = 0; r < 16; ++r)
    out[(m0 + r) * H + j] = acc[r] + bsum;
}

// ---------------------------------------------------------------------------
// K2/K4: sequential scan. One WG (1024 thr, 16 waves) per batch element.
// Layout (J=4,K=16): lane = ks(bits2-5) x oq(bits0-1); thread owns outputs
// j = wave*16 + oq*4 + {0..3} and k-slice [ks*16, ks*16+16).
//  - h read: 4 x ds_read_b128 per thread (64 B) => LDS return traffic
//    64 KB/CU/step (was 256 KB in R4's J=1 layout -- the real 2062cyc bound).
//  - w: 64 floats in VGPRs; residency forced 3 ways: waves_per_eu(4,4),
//    amdgpu_num_vgpr(128), and PER-ITERATION asm pins (loop-variant values
//    cannot be rematerialized; spilling would cost store+load per step).
//  - reduce: in-wave shfl_xor over ks bits (masks 4,8,16,32) -- no LDS
//    part[] round-trip, ONE barrier per step.
//  - h LDS layout: 16 groups of (16 floats + 2 pad) => b128 reads touch each
//    bank exactly 2x (2-way aliasing is free, m136).
// ---------------------------------------------------------------------------
__global__ __attribute__((amdgpu_flat_work_group_size(1024, 1024),
                          amdgpu_waves_per_eu(4, 4), amdgpu_num_vgpr(128)))
void rnn_scan(const float* __restrict__ pre, const float* __restrict__ W_hh,
              float* __restrict__ hout) {
  __shared__ float h_lds[2][16 * 18];  // double-buffered, 18-word groups

  const int tid  = threadIdx.x;
  const int lane = tid & 63;
  const int wv   = tid >> 6;           // 0..15
  const int oq   = lane & 3;           // output quad within wave
  const int ks   = lane >> 2;          // 0..15 k-slice
  const int jb   = wv * 16 + oq * 4;   // first of this thread's 4 outputs
  const int b    = blockIdx.x;

  // W_hh rows jb..jb+3, k in [ks*16, ks*16+16) -> 64 floats in VGPRs
  const float4* W4 = (const float4*)W_hh;
  float w[4][16];
#pragma unroll
  for (int a = 0; a < 4; ++a)
#pragma unroll
    for (int m = 0; m < 4; ++m) {
      float4 t = W4[(long)(jb + a) * (H / 4) + ks * 4 + m];
      w[a][4 * m + 0] = t.x; w[a][4 * m + 1] = t.y;
      w[a][4 * m + 2] = t.z; w[a][4 * m + 3] = t.w;
    }

  if (tid < 2 * 16 * 18) ((float*)h_lds)[tid] = 0.f;  // zero both buffers

  const float4* prej4 = (const float4*)(pre + (long)b * T * H) + (jb >> 2);
  float*        houtj = hout + (long)b * T * H + jb;
  float4 p0 = prej4[0], p1 = prej4[64];
  __syncthreads();

#pragma unroll 1
  for (int t = 0; t < T; ++t) {
    float4 p2;
    p2.x = p2.y = p2.z = p2.w = 0.f;
    if (t + 2 < T) p2 = prej4[(long)(t + 2) * 64];   // dist-2 prefetch

    // Pin w every iteration: loop-variant => no remat, spill = store+load.
#pragma unroll
    for (int a = 0; a < 4; ++a) {
      asm volatile("" : "+v"(w[a][0]), "+v"(w[a][1]), "+v"(w[a][2]), "+v"(w[a][3]),
                         "+v"(w[a][4]), "+v"(w[a][5]), "+v"(w[a][6]), "+v"(w[a][7]),
                         "+v"(w[a][8]), "+v"(w[a][9]), "+v"(w[a][10]), "+v"(w[a][11]),
                         "+v"(w[a][12]), "+v"(w[a][13]), "+v"(w[a][14]), "+v"(w[a][15]));
    }

    const float4* hb = (const float4*)&h_lds[t & 1][ks * 18];
    float4 h0 = hb[0], h1 = hb[1], h2 = hb[2], h3 = hb[3];

    float s[4];
#pragma unroll
    for (int a = 0; a < 4; ++a) {
      float acc0 = w[a][0] * h0.x + w[a][2] * h0.z;
      float acc1 = w[a][1] * h0.y + w[a][3] * h0.w;
      acc0 += w[a][4]  * h1.x; acc1 += w[a][5]  * h1.y;
      acc0 += w[a][6]  * h1.z; acc1 += w[a][7]  * h1.w;
      acc0 += w[a][8]  * h2.x; acc1 += w[a][9]  * h2.y;
      acc0 += w[a][10] * h2.z; acc1 += w[a][11] * h2.w;
      acc0 += w[a][12] * h3.x; acc1 += w[a][13] * h3.y;
      acc0 += w[a][14] * h3.z; acc1 += w[a][15] * h3.w;
      s[a] = acc0 + acc1;
    }

    // In-wave reduction over ks (lane bits 2..5)
#pragma unroll
    for (int a = 0; a < 4; ++a) {
      float v = s[a];
      v += __shfl_xor(v, 4, 64);
      v += __shfl_xor(v, 8, 64);
      v += __shfl_xor(v, 16, 64);
      v += __shfl_xor(v, 32, 64);
      s[a] = v;
    }

    float4 hn;
    {
      float x0 = p0.x + s[0], x1 = p0.y + s[1], x2 = p0.z + s[2], x3 = p0.w + s[3];
      float e0 = __expf(2.f * x0), e1 = __expf(2.f * x1);
      float e2 = __expf(2.f * x2), e3 = __expf(2.f * x3);
      hn.x = 1.f - 2.f * __builtin_amdgcn_rcpf(e0 + 1.f);
      hn.y = 1.f - 2.f * __builtin_amdgcn_rcpf(e1 + 1.f);
      hn.z = 1.f - 2.f * __builtin_amdgcn_rcpf(e2 + 1.f);
      hn.w = 1.f - 2.f * __builtin_amdgcn_rcpf(e3 + 1.f);
    }

    if (ks == 0) {
      // j = wv*16 + oq*4 + r  ->  LDS word wv*18 + oq*4 + r (group = wv)
      *(float4*)&h_lds[(t + 1) & 1][wv * 18 + oq * 4] = hn;
      *(float4*)(houtj + (long)t * H) = hn;        // coalesced 64B/wave
    }
    p0 = p1; p1 = p2;
    __syncthreads();                               // single barrier per step
  }
}

// ---------------------------------------------------------------------------
// K5: out[m][p] = sigmoid( sum_j h2[m][j]*fcW[p][j] + fcb[p] )
// ---------------------------------------------------------------------------
__global__ __launch_bounds__(256) void fc_sigmoid(
    const float* __restrict__ h2, const float* __restrict__ fcW,
    const float* __restrict__ fcb, float* __restrict__ out) {
  __shared__ float h2l[16][H];
  const int tid = threadIdx.x;
  const long m0 = (long)blockIdx.x * 16;

  const float4* H4 = (const float4*)h2;
#pragma unroll
  for (int i = 0; i < 4; ++i) {
    int idx = tid + 256 * i;
    int r = idx >> 6, c4 = idx & 63;
    *(float4*)&h2l[r][4 * c4] = H4[(m0 + r) * (H / 4) + c4];
  }
  __syncthreads();

  const int p = tid & 63, rq = tid >> 6;
  const float4* W4 = (const float4*)fcW;
  float acc[4] = {0.f, 0.f, 0.f, 0.f};
#pragma unroll 8
  for (int c4 = 0; c4 < H / 4; ++c4) {
    float4 wv = W4[(long)p * (H / 4) + c4];
#pragma unroll
    for (int k = 0; k < 4; ++k) {
      float4 av = *(const float4*)&h2l[rq * 4 + k][4 * c4];
      acc[k] += wv.x * av.x + wv.y * av.y + wv.z * av.z + wv.w * av.w;
    }
  }
  const float bb = fcb[p];
#pragma unroll
  for (int k = 0; k < 4; ++k) {
    float x = acc[k] + bb;
    out[(m0 + rq * 4 + k) * P + p] = 1.f / (1.f + __expf(-x));
  }
}

// ---------------------------------------------------------------------------
extern "C" void kernel_launch(void* const* d_in, const int* in_sizes, int n_in,
                              void* d_out, int out_size, void* d_ws, size_t ws_size,
                              hipStream_t stream) {
  const float* input = (const float*)d_in[0];
  const float* W_ih0 = (const float*)d_in[1];
  const float* W_hh0 = (const float*)d_in[2];
  const float* b_ih0 = (const float*)d_in[3];
  const float* b_hh0 = (const float*)d_in[4];
  const float* W_ih1 = (const float*)d_in[5];
  const float* W_hh1 = (const float*)d_in[6];
  const float* b_ih1 = (const float*)d_in[7];
  const float* b_hh1 = (const float*)d_in[8];
  const float* fc_W  = (const float*)d_in[9];
  const float* fc_b  = (const float*)d_in[10];
  float* out = (float*)d_out;

  float* bufA = (float*)d_ws;                 // pre0 -> pre1
  float* bufB = bufA + (size_t)M * H;         // h1 -> h2

  gemm_pre<IN><<<(int)(M / 16), 256, 0, stream>>>(input, W_ih0, b_ih0, b_hh0, bufA);
  rnn_scan<<<Bsz, 1024, 0, stream>>>(bufA, W_hh0, bufB);
  gemm_pre<H><<<(int)(M / 16), 256, 0, stream>>>(bufB, W_ih1, b_ih1, b_hh1, bufA);
  rnn_scan<<<Bsz, 1024, 0, stream>>>(bufA, W_hh1, bufB);
  fc_sigmoid<<<(int)(M / 16), 256, 0, stream>>>(bufB, fc_W, fc_b, out);
}

// Round 6
// 10277.177 us; speedup vs baseline: 2.2166x; 2.2166x over previous
//
#include <hip/hip_runtime.h>
#include <hip/hip_bf16.h>

// Problem constants (match reference)
constexpr int Bsz = 32;
constexpr int T   = 4096;
constexpr int P   = 64;
constexpr int IN  = 128;
constexpr int H   = 256;
constexpr long M  = (long)Bsz * T;   // 131072 rows

// ---------------------------------------------------------------------------
// K1/K3: out[m][j] = sum_c X[m][c] * W[j][c] + b1[j] + b2[j]
// ---------------------------------------------------------------------------
template <int K>
__global__ __launch_bounds__(256) void gemm_pre(
    const float* __restrict__ X, const float* __restrict__ W,
    const float* __restrict__ b1, const float* __restrict__ b2,
    float* __restrict__ out) {
  constexpr int K4 = K / 4;
  __shared__ float4 a4[16][K4];
  __shared__ float  wch[256][33];
  const int tid = threadIdx.x;
  const long m0 = (long)blockIdx.x * 16;

  const float4* X4 = (const float4*)X;
#pragma unroll
  for (int i = 0; i < (16 * K4) / 256; ++i) {
    int idx = tid + 256 * i;
    int r = idx / K4, c = idx % K4;
    a4[r][c] = X4[(m0 + r) * K4 + c];
  }

  const int j = tid;
  const float bsum = b1[j] + b2[j];
  float acc[16];
#pragma unroll
  for (int r = 0; r < 16; ++r) acc[r] = 0.f;

  const float4* W4v = (const float4*)W;
  for (int kc = 0; kc < K4; kc += 8) {
    __syncthreads();
#pragma unroll
    for (int i = 0; i < 8; ++i) {
      int idx = tid + 256 * i;
      int jr = idx >> 3, c = idx & 7;
      float4 t4 = W4v[(long)jr * K4 + kc + c];
      wch[jr][4 * c + 0] = t4.x; wch[jr][4 * c + 1] = t4.y;
      wch[jr][4 * c + 2] = t4.z; wch[jr][4 * c + 3] = t4.w;
    }
    __syncthreads();
#pragma unroll
    for (int i4 = 0; i4 < 8; ++i4) {
      float wx = wch[j][4 * i4 + 0], wy = wch[j][4 * i4 + 1];
      float wz = wch[j][4 * i4 + 2], ww = wch[j][4 * i4 + 3];
#pragma unroll
      for (int r = 0; r < 16; ++r) {
        float4 av = a4[r][kc + i4];
        acc[r] += wx * av.x + wy * av.y + wz * av.z + ww * av.w;
      }
    }
  }
#pragma unroll
  for (int r = 0; r < 16; ++r)
    out[(m0 + r) * H + j] = acc[r] + bsum;
}

// ---------------------------------------------------------------------------
// K2/K4: sequential scan. One WG (1024 thr, 16 waves) per batch element.
// Layout (J=4,K=16): lane = ks(bits2-5) x oq(bits0-1); thread owns outputs
// j = wv*16 + oq*4 + {0..3} and k-slice [ks*16, ks*16+16).
//
// THE FIX: 96 KB static LDS forces 1 WG/CU at COMPILE time, so the backend's
// occupancy target drops to 4 waves/EU => 128-VGPR budget => w[64] stays
// resident. (R1/R3/R4/R5 evidence: with tiny LDS the allocator targets
// 2 WGs/CU = 64 VGPRs for 1024-thr blocks and spills w to scratch, ignoring
// waves_per_eu/num_vgpr attributes.) Runtime cost: zero -- only 32 WGs on
// 256 CUs, there was never a second WG per CU.
//
// h double-buffer lives in the front of the big array: 16 groups of
// (16 floats + 4 pad) = 20 words -> b128 reads are 16B-aligned (R5's 18-word
// groups were NOT, forcing split ds_reads) and 2-way bank aliased (free).
// One barrier/step; in-wave shfl_xor reduction over ks; dist-2 prefetch.
// ---------------------------------------------------------------------------
__global__ __launch_bounds__(1024) void rnn_scan(
    const float* __restrict__ pre, const float* __restrict__ W_hh,
    float* __restrict__ hout) {
  __shared__ float big[24576];         // 96 KB: occupancy limiter + h bufs
  float* hb0 = big;                    // h buffer 0: 16 groups * 20 words
  float* hb1 = big + 320;              // h buffer 1

  const int tid  = threadIdx.x;
  const int lane = tid & 63;
  const int wv   = tid >> 6;           // 0..15
  const int oq   = lane & 3;           // output quad within wave
  const int ks   = lane >> 2;          // 0..15 k-slice
  const int jb   = wv * 16 + oq * 4;   // first of this thread's 4 outputs
  const int b    = blockIdx.x;

  // W_hh rows jb..jb+3, k in [ks*16, ks*16+16) -> 64 floats in VGPRs
  const float4* W4 = (const float4*)W_hh;
  float w[4][16];
#pragma unroll
  for (int a = 0; a < 4; ++a) {
#pragma unroll
    for (int m = 0; m < 4; ++m) {
      float4 t = W4[(long)(jb + a) * (H / 4) + ks * 4 + m];
      w[a][4 * m + 0] = t.x; w[a][4 * m + 1] = t.y;
      w[a][4 * m + 2] = t.z; w[a][4 * m + 3] = t.w;
    }
    __builtin_amdgcn_sched_barrier(0); // cap in-flight loads: no pressure spike
  }
  // One-time opaque pin: no remat possible; with the 128-reg budget there is
  // no reason to spill either.
#pragma unroll
  for (int a = 0; a < 4; ++a) {
    asm volatile("" : "+v"(w[a][0]), "+v"(w[a][1]), "+v"(w[a][2]), "+v"(w[a][3]),
                       "+v"(w[a][4]), "+v"(w[a][5]), "+v"(w[a][6]), "+v"(w[a][7]),
                       "+v"(w[a][8]), "+v"(w[a][9]), "+v"(w[a][10]), "+v"(w[a][11]),
                       "+v"(w[a][12]), "+v"(w[a][13]), "+v"(w[a][14]), "+v"(w[a][15]));
  }

  if (tid < 640) big[tid] = 0.f;       // zero both h buffers

  const float4* prej4 = (const float4*)(pre + (long)b * T * H) + (jb >> 2);
  float*        houtj = hout + (long)b * T * H + jb;
  float4 p0 = prej4[0], p1 = prej4[64];
  __syncthreads();

#pragma unroll 1
  for (int t = 0; t < T; ++t) {
    float4 p2;
    p2.x = p2.y = p2.z = p2.w = 0.f;
    if (t + 2 < T) p2 = prej4[(long)(t + 2) * 64];  // dist-2 prefetch

    const float4* hb4 =
        (const float4*)(((t & 1) ? hb1 : hb0) + ks * 20);
    float4 h0 = hb4[0], h1 = hb4[1], h2 = hb4[2], h3 = hb4[3];

    float s[4];
#pragma unroll
    for (int a = 0; a < 4; ++a) {
      float acc0 = w[a][0] * h0.x + w[a][2] * h0.z;
      float acc1 = w[a][1] * h0.y + w[a][3] * h0.w;
      acc0 += w[a][4]  * h1.x; acc1 += w[a][5]  * h1.y;
      acc0 += w[a][6]  * h1.z; acc1 += w[a][7]  * h1.w;
      acc0 += w[a][8]  * h2.x; acc1 += w[a][9]  * h2.y;
      acc0 += w[a][10] * h2.z; acc1 += w[a][11] * h2.w;
      acc0 += w[a][12] * h3.x; acc1 += w[a][13] * h3.y;
      acc0 += w[a][14] * h3.z; acc1 += w[a][15] * h3.w;
      s[a] = acc0 + acc1;
    }

    // In-wave reduction over ks (lane bits 2..5)
#pragma unroll
    for (int a = 0; a < 4; ++a) {
      float v = s[a];
      v += __shfl_xor(v, 4, 64);
      v += __shfl_xor(v, 8, 64);
      v += __shfl_xor(v, 16, 64);
      v += __shfl_xor(v, 32, 64);
      s[a] = v;
    }

    float4 hn;
    {
      float x0 = p0.x + s[0], x1 = p0.y + s[1], x2 = p0.z + s[2], x3 = p0.w + s[3];
      float e0 = __expf(2.f * x0), e1 = __expf(2.f * x1);
      float e2 = __expf(2.f * x2), e3 = __expf(2.f * x3);
      hn.x = 1.f - 2.f * __builtin_amdgcn_rcpf(e0 + 1.f);
      hn.y = 1.f - 2.f * __builtin_amdgcn_rcpf(e1 + 1.f);
      hn.z = 1.f - 2.f * __builtin_amdgcn_rcpf(e2 + 1.f);
      hn.w = 1.f - 2.f * __builtin_amdgcn_rcpf(e3 + 1.f);
    }

    if (ks == 0) {
      float* hw = ((t & 1) ? hb0 : hb1);           // next-step buffer
      *(float4*)(hw + wv * 20 + oq * 4) = hn;      // h[jb..jb+3]
      *(float4*)(houtj + (long)t * H) = hn;        // coalesced 64B/wave
    }
    p0 = p1; p1 = p2;
    __syncthreads();                               // single barrier per step
  }
}

// ---------------------------------------------------------------------------
// K5: out[m][p] = sigmoid( sum_j h2[m][j]*fcW[p][j] + fcb[p] )
// ---------------------------------------------------------------------------
__global__ __launch_bounds__(256) void fc_sigmoid(
    const float* __restrict__ h2, const float* __restrict__ fcW,
    const float* __restrict__ fcb, float* __restrict__ out) {
  __shared__ float h2l[16][H];
  const int tid = threadIdx.x;
  const long m0 = (long)blockIdx.x * 16;

  const float4* H4 = (const float4*)h2;
#pragma unroll
  for (int i = 0; i < 4; ++i) {
    int idx = tid + 256 * i;
    int r = idx >> 6, c4 = idx & 63;
    *(float4*)&h2l[r][4 * c4] = H4[(m0 + r) * (H / 4) + c4];
  }
  __syncthreads();

  const int p = tid & 63, rq = tid >> 6;
  const float4* W4 = (const float4*)fcW;
  float acc[4] = {0.f, 0.f, 0.f, 0.f};
#pragma unroll 8
  for (int c4 = 0; c4 < H / 4; ++c4) {
    float4 wv = W4[(long)p * (H / 4) + c4];
#pragma unroll
    for (int k = 0; k < 4; ++k) {
      float4 av = *(const float4*)&h2l[rq * 4 + k][4 * c4];
      acc[k] += wv.x * av.x + wv.y * av.y + wv.z * av.z + wv.w * av.w;
    }
  }
  const float bb = fcb[p];
#pragma unroll
  for (int k = 0; k < 4; ++k) {
    float x = acc[k] + bb;
    out[(m0 + rq * 4 + k) * P + p] = 1.f / (1.f + __expf(-x));
  }
}

// ---------------------------------------------------------------------------
extern "C" void kernel_launch(void* const* d_in, const int* in_sizes, int n_in,
                              void* d_out, int out_size, void* d_ws, size_t ws_size,
                              hipStream_t stream) {
  const float* input = (const float*)d_in[0];
  const float* W_ih0 = (const float*)d_in[1];
  const float* W_hh0 = (const float*)d_in[2];
  const float* b_ih0 = (const float*)d_in[3];
  const float* b_hh0 = (const float*)d_in[4];
  const float* W_ih1 = (const float*)d_in[5];
  const float* W_hh1 = (const float*)d_in[6];
  const float* b_ih1 = (const float*)d_in[7];
  const float* b_hh1 = (const float*)d_in[8];
  const float* fc_W  = (const float*)d_in[9];
  const float* fc_b  = (const float*)d_in[10];
  float* out = (float*)d_out;

  float* bufA = (float*)d_ws;                 // pre0 -> pre1
  float* bufB = bufA + (size_t)M * H;         // h1 -> h2

  gemm_pre<IN><<<(int)(M / 16), 256, 0, stream>>>(input, W_ih0, b_ih0, b_hh0, bufA);
  rnn_scan<<<Bsz, 1024, 0, stream>>>(bufA, W_hh0, bufB);
  gemm_pre<H><<<(int)(M / 16), 256, 0, stream>>>(bufB, W_ih1, b_ih1, b_hh1, bufA);
  rnn_scan<<<Bsz, 1024, 0, stream>>>(bufA, W_hh1, bufB);
  fc_sigmoid<<<(int)(M / 16), 256, 0, stream>>>(bufB, fc_W, fc_b, out);
}

// Round 7
// 9315.660 us; speedup vs baseline: 2.4454x; 1.1032x over previous
//
#include <hip/hip_runtime.h>
#include <hip/hip_bf16.h>

typedef float v2f __attribute__((ext_vector_type(2)));

// Problem constants (match reference)
constexpr int Bsz = 32;
constexpr int T   = 4096;
constexpr int P   = 64;
constexpr int IN  = 128;
constexpr int H   = 256;
constexpr long M  = (long)Bsz * T;   // 131072 rows

// DPP row_shr:N add (bound_ctrl: OOB lanes contribute 0). VALU pipe only.
template <int CTRL>
__device__ __forceinline__ float dpp_add(float x) {
  int y = __builtin_amdgcn_update_dpp(0, __builtin_bit_cast(int, x),
                                      CTRL, 0xf, 0xf, true);
  return x + __builtin_bit_cast(float, y);
}

// ---------------------------------------------------------------------------
// K1/K3: out[m][j] = sum_c X[m][c] * W[j][c] + b1[j] + b2[j]
// ---------------------------------------------------------------------------
template <int K>
__global__ __launch_bounds__(256) void gemm_pre(
    const float* __restrict__ X, const float* __restrict__ W,
    const float* __restrict__ b1, const float* __restrict__ b2,
    float* __restrict__ out) {
  constexpr int K4 = K / 4;
  __shared__ float4 a4[16][K4];
  __shared__ float  wch[256][33];
  const int tid = threadIdx.x;
  const long m0 = (long)blockIdx.x * 16;

  const float4* X4 = (const float4*)X;
#pragma unroll
  for (int i = 0; i < (16 * K4) / 256; ++i) {
    int idx = tid + 256 * i;
    int r = idx / K4, c = idx % K4;
    a4[r][c] = X4[(m0 + r) * K4 + c];
  }

  const int j = tid;
  const float bsum = b1[j] + b2[j];
  float acc[16];
#pragma unroll
  for (int r = 0; r < 16; ++r) acc[r] = 0.f;

  const float4* W4v = (const float4*)W;
  for (int kc = 0; kc < K4; kc += 8) {
    __syncthreads();
#pragma unroll
    for (int i = 0; i < 8; ++i) {
      int idx = tid + 256 * i;
      int jr = idx >> 3, c = idx & 7;
      float4 t4 = W4v[(long)jr * K4 + kc + c];
      wch[jr][4 * c + 0] = t4.x; wch[jr][4 * c + 1] = t4.y;
      wch[jr][4 * c + 2] = t4.z; wch[jr][4 * c + 3] = t4.w;
    }
    __syncthreads();
#pragma unroll
    for (int i4 = 0; i4 < 8; ++i4) {
      float wx = wch[j][4 * i4 + 0], wy = wch[j][4 * i4 + 1];
      float wz = wch[j][4 * i4 + 2], ww = wch[j][4 * i4 + 3];
#pragma unroll
      for (int r = 0; r < 16; ++r) {
        float4 av = a4[r][kc + i4];
        acc[r] += wx * av.x + wy * av.y + wz * av.z + ww * av.w;
      }
    }
  }
#pragma unroll
  for (int r = 0; r < 16; ++r)
    out[(m0 + r) * H + j] = acc[r] + bsum;
}

// ---------------------------------------------------------------------------
// K2/K4: sequential scan. One WG (1024 thr, 16 waves) per batch element.
// Lane map: ks = lane&15 (k-slice), oq = lane>>4 (output quad).
// Thread: outputs j = wv*16+oq*4+{0..3}, k in [ks*16, ks*16+16).
//  - dot partials: float2 math -> v_pk_fma_f32 (32 packed FMA, half the
//    issue slots of 64 scalar).
//  - reduce over ks = lane bits 0..3 via DPP row_shr 1/2/4/8 adds (VALU
//    pipe) -> lane 15 of each 16-row holds the full dot. ZERO LDS ops
//    (R6's 16 ds_swizzles/thread saturated the per-CU DS pipe).
//  - h: plain [2][256] double buffer, aligned b128 reads (broadcast x4,
//    2-way bank alias = free), one write by ks==15 lanes, 1 barrier/step.
//  - no pins / no attributes: R1-R6 showed the allocator parks w in the
//    unified-file AGPRs regardless (no scratch spill: WRITE_SIZE exact);
//    we accept the accvgpr-read tax this round and cut everything else.
// ---------------------------------------------------------------------------
__global__ __launch_bounds__(1024) void rnn_scan(
    const float* __restrict__ pre, const float* __restrict__ W_hh,
    float* __restrict__ hout) {
  __shared__ float h_lds[2][256];

  const int tid  = threadIdx.x;
  const int lane = tid & 63;
  const int wv   = tid >> 6;           // 0..15
  const int ks   = lane & 15;          // k-slice (reduction dim, bits 0..3)
  const int oq   = lane >> 4;          // output quad (bits 4..5)
  const int jb   = wv * 16 + oq * 4;   // first of this thread's 4 outputs
  const int b    = blockIdx.x;

  // W_hh rows jb..jb+3, k in [ks*16, ks*16+16) -> 32 float2 in VGPRs
  const float4* W4 = (const float4*)W_hh;
  v2f w2[4][8];
#pragma unroll
  for (int a = 0; a < 4; ++a)
#pragma unroll
    for (int m = 0; m < 4; ++m) {
      float4 t = W4[(long)(jb + a) * (H / 4) + ks * 4 + m];
      w2[a][2 * m + 0] = v2f{t.x, t.y};
      w2[a][2 * m + 1] = v2f{t.z, t.w};
    }

  if (tid < 512) ((float*)h_lds)[tid] = 0.f;   // zero both buffers

  const float4* prej4 = (const float4*)(pre + (long)b * T * H) + (jb >> 2);
  float*        houtj = hout + (long)b * T * H + jb;
  float4 p0 = prej4[0], p1 = prej4[64];
  __syncthreads();

#pragma unroll 1
  for (int t = 0; t < T; ++t) {
    float4 p2;
    p2.x = p2.y = p2.z = p2.w = 0.f;
    if (t + 2 < T) p2 = prej4[(long)(t + 2) * 64];   // dist-2 prefetch

    const float4* hb4 = (const float4*)(h_lds[t & 1] + ks * 16);
    float4 h0 = hb4[0], h1 = hb4[1], h2 = hb4[2], h3 = hb4[3];
    v2f hh[8];
    hh[0] = v2f{h0.x, h0.y}; hh[1] = v2f{h0.z, h0.w};
    hh[2] = v2f{h1.x, h1.y}; hh[3] = v2f{h1.z, h1.w};
    hh[4] = v2f{h2.x, h2.y}; hh[5] = v2f{h2.z, h2.w};
    hh[6] = v2f{h3.x, h3.y}; hh[7] = v2f{h3.z, h3.w};

    float s[4];
#pragma unroll
    for (int a = 0; a < 4; ++a) {
      v2f acc0 = w2[a][0] * hh[0];
      v2f acc1 = w2[a][1] * hh[1];
#pragma unroll
      for (int m = 2; m < 8; m += 2) {
        acc0 += w2[a][m + 0] * hh[m + 0];
        acc1 += w2[a][m + 1] * hh[m + 1];
      }
      v2f acc = acc0 + acc1;
      s[a] = acc.x + acc.y;
    }

    // Sum over ks (lane bits 0..3) on the VALU pipe: row_shr prefix cascade;
    // lane 15 of each 16-row ends with the full 256-term dot.
#pragma unroll
    for (int a = 0; a < 4; ++a) {
      float v = s[a];
      v = dpp_add<0x111>(v);   // row_shr:1
      v = dpp_add<0x112>(v);   // row_shr:2
      v = dpp_add<0x114>(v);   // row_shr:4
      v = dpp_add<0x118>(v);   // row_shr:8
      s[a] = v;
    }

    // tanh (valid only in ks==15 lanes; others compute garbage, don't store)
    float4 hn;
    {
      float x0 = p0.x + s[0], x1 = p0.y + s[1], x2 = p0.z + s[2], x3 = p0.w + s[3];
      float e0 = __expf(2.f * x0), e1 = __expf(2.f * x1);
      float e2 = __expf(2.f * x2), e3 = __expf(2.f * x3);
      hn.x = 1.f - 2.f * __builtin_amdgcn_rcpf(e0 + 1.f);
      hn.y = 1.f - 2.f * __builtin_amdgcn_rcpf(e1 + 1.f);
      hn.z = 1.f - 2.f * __builtin_amdgcn_rcpf(e2 + 1.f);
      hn.w = 1.f - 2.f * __builtin_amdgcn_rcpf(e3 + 1.f);
    }

    if (ks == 15) {
      *(float4*)&h_lds[(t + 1) & 1][jb] = hn;
      *(float4*)(houtj + (long)t * H) = hn;          // 64B per wave
    }
    p0 = p1; p1 = p2;
    __syncthreads();                                 // single barrier per step
  }
}

// ---------------------------------------------------------------------------
// K5: out[m][p] = sigmoid( sum_j h2[m][j]*fcW[p][j] + fcb[p] )
// ---------------------------------------------------------------------------
__global__ __launch_bounds__(256) void fc_sigmoid(
    const float* __restrict__ h2, const float* __restrict__ fcW,
    const float* __restrict__ fcb, float* __restrict__ out) {
  __shared__ float h2l[16][H];
  const int tid = threadIdx.x;
  const long m0 = (long)blockIdx.x * 16;

  const float4* H4 = (const float4*)h2;
#pragma unroll
  for (int i = 0; i < 4; ++i) {
    int idx = tid + 256 * i;
    int r = idx >> 6, c4 = idx & 63;
    *(float4*)&h2l[r][4 * c4] = H4[(m0 + r) * (H / 4) + c4];
  }
  __syncthreads();

  const int p = tid & 63, rq = tid >> 6;
  const float4* W4 = (const float4*)fcW;
  float acc[4] = {0.f, 0.f, 0.f, 0.f};
#pragma unroll 8
  for (int c4 = 0; c4 < H / 4; ++c4) {
    float4 wv = W4[(long)p * (H / 4) + c4];
#pragma unroll
    for (int k = 0; k < 4; ++k) {
      float4 av = *(const float4*)&h2l[rq * 4 + k][4 * c4];
      acc[k] += wv.x * av.x + wv.y * av.y + wv.z * av.z + wv.w * av.w;
    }
  }
  const float bb = fcb[p];
#pragma unroll
  for (int k = 0; k < 4; ++k) {
    float x = acc[k] + bb;
    out[(m0 + rq * 4 + k) * P + p] = 1.f / (1.f + __expf(-x));
  }
}

// ---------------------------------------------------------------------------
extern "C" void kernel_launch(void* const* d_in, const int* in_sizes, int n_in,
                              void* d_out, int out_size, void* d_ws, size_t ws_size,
                              hipStream_t stream) {
  const float* input = (const float*)d_in[0];
  const float* W_ih0 = (const float*)d_in[1];
  const float* W_hh0 = (const float*)d_in[2];
  const float* b_ih0 = (const float*)d_in[3];
  const float* b_hh0 = (const float*)d_in[4];
  const float* W_ih1 = (const float*)d_in[5];
  const float* W_hh1 = (const float*)d_in[6];
  const float* b_ih1 = (const float*)d_in[7];
  const float* b_hh1 = (const float*)d_in[8];
  const float* fc_W  = (const float*)d_in[9];
  const float* fc_b  = (const float*)d_in[10];
  float* out = (float*)d_out;

  float* bufA = (float*)d_ws;                 // pre0 -> pre1
  float* bufB = bufA + (size_t)M * H;         // h1 -> h2

  gemm_pre<IN><<<(int)(M / 16), 256, 0, stream>>>(input, W_ih0, b_ih0, b_hh0, bufA);
  rnn_scan<<<Bsz, 1024, 0, stream>>>(bufA, W_hh0, bufB);
  gemm_pre<H><<<(int)(M / 16), 256, 0, stream>>>(bufB, W_ih1, b_ih1, b_hh1, bufA);
  rnn_scan<<<Bsz, 1024, 0, stream>>>(bufA, W_hh1, bufB);
  fc_sigmoid<<<(int)(M / 16), 256, 0, stream>>>(bufB, fc_W, fc_b, out);
}